// Round 5
// baseline (230.812 us; speedup 1.0000x reference)
//
#include <hip/hip_runtime.h>

// CIN (xDeepFM) fully-fused kernel for MI355X.
// B=4096, F=32, D=32; layer1: K1=1024 -> N=128; layer2: K2=4096 -> N=128.
// GEMM rows=(b,d); A generated in registers: A[(b,d)][h*M+m] = x0[b,h,d]*prev[b,m,d].
// mfma_f32_32x32x16_f16.
// R10 reorder / R11 setprio / R13 pinned-interleave: all null-or-negative at
// 2 waves/SIMD. R13 falsified the phase-lock theory (both utils dropped
// proportionally). In-order-issue analysis says 2 waves should already
// overlap to ~94% -- the residual ~36% idle must be per-wave stalls that
// source-level scheduling can't remove. R14: the TLP lever. Wave tile
// rt=2 x ct=2 (2b x 64n): acc 64 AGPR (same 2 pk_mul/MFMA, same 0.5
// B-load/MFMA ratios), JIT B loads (no ping-pong; 4-way TLP hides L1
// latency), total ~110-125 regs -> 4 waves/SIMD (launch_bounds(256,4)).
// Block = 4b x 128n (4 waves: b-pair x col-half), LDS 40 KB, grid 1024 =
// exactly 4 blocks/CU x 256 CU (no tail). No sched pragmas (R13 lesson).

typedef _Float16 half_t;
typedef _Float16 half4v __attribute__((ext_vector_type(4)));
typedef _Float16 half8 __attribute__((ext_vector_type(8)));
typedef float f32x16 __attribute__((ext_vector_type(16)));

// ---- W pack (both filters, one launch): Wp[s][tg][n][8], k=h*M+mc*16+tg*8+j.
__global__ void prep_w_kernel(const float* __restrict__ W0,
                              const float* __restrict__ W1,
                              half_t* __restrict__ Wp0,
                              half_t* __restrict__ Wp1) {
  int gid = blockIdx.x * 256 + threadIdx.x;  // 320*256 threads
  int n = gid & 127;
  int tg = (gid >> 7) & 1;
  int s = gid >> 8;  // 0..319
  const float* W;
  half_t* Wp;
  int M, sl;
  if (s < 64) { W = W0; Wp = Wp0; M = 32; sl = s; }
  else        { W = W1; Wp = Wp1; M = 128; sl = s - 64; }
  int h = sl & 31, mc = sl >> 5;
  int kbase = h * M + mc * 16 + tg * 8;
  half8 v;
#pragma unroll
  for (int j = 0; j < 8; ++j) v[j] = (half_t)W[(size_t)(kbase + j) * 128 + n];
  *(half8*)(Wp + ((size_t)(sl * 2 + tg) * 128 + n) * 8) = v;
}

// swizzled prevT index: logical (row, m) -> halfs offset. 16B-chunk XOR spread.
__device__ __forceinline__ int pswz(int row, int m) {
  return row * 128 + (((m >> 3) ^ (row & 15)) << 3) + (m & 7);
}

__device__ __forceinline__ f32x16 mfma3216(half8 a, half8 b, f32x16 c) {
  return __builtin_amdgcn_mfma_f32_32x32x16_f16(a, b, c, 0, 0, 0);
}

// One CIN layer: MC m-chunks x 32 h. Per p: one xq half8 (covers all 4 h),
// 2 gg's of {4 JIT B loads, 4 pk_mul frags, 8 MFMA}. Compiler schedules
// freely; 4 waves/SIMD provide the latency cover.
template <int MC, bool L1>
__device__ __forceinline__ void layer_loop(const half_t* __restrict__ Wp,
                                           const half_t* __restrict__ psrc,
                                           const half_t* __restrict__ xQw,
                                           int woff0, int woff1, int rowb,
                                           int l31, int hi, f32x16 acc[2][2]) {
  half8 P[2];
#pragma unroll
  for (int rt = 0; rt < 2; ++rt)
    P[rt] = L1 ? *(const half8*)&psrc[(rowb + rt * 32 + l31) * 40 + hi * 8]
               : *(const half8*)&psrc[pswz(rowb + rt * 32 + l31, hi * 8)];

#pragma unroll 1
  for (int mc = 0; mc < MC; ++mc) {
#pragma unroll 1
    for (int p = 0; p < 8; ++p) {
      const int sb = mc * 32 + 4 * p;  // base s-step; s = mc*32 + h
      half8 xq = *(const half8*)(xQw + p * 256);
      // ---- even gg: h = 4p (B0*), 4p+1 (B1*) ----
      {
        half8 B00 = *(const half8*)(Wp + (size_t)(sb + 0) * 2048 + woff0);
        half8 B01 = *(const half8*)(Wp + (size_t)(sb + 0) * 2048 + woff1);
        half8 B10 = *(const half8*)(Wp + (size_t)(sb + 1) * 2048 + woff0);
        half8 B11 = *(const half8*)(Wp + (size_t)(sb + 1) * 2048 + woff1);
        half8 A00 = P[0] * xq[0];  // rt0, h=4p
        half8 A10 = P[1] * xq[2];  // rt1, h=4p
        half8 A01 = P[0] * xq[1];  // rt0, h=4p+1
        half8 A11 = P[1] * xq[3];  // rt1, h=4p+1
        acc[0][0] = mfma3216(A00, B00, acc[0][0]);
        acc[0][1] = mfma3216(A00, B01, acc[0][1]);
        acc[1][0] = mfma3216(A10, B00, acc[1][0]);
        acc[1][1] = mfma3216(A10, B01, acc[1][1]);
        acc[0][0] = mfma3216(A01, B10, acc[0][0]);
        acc[0][1] = mfma3216(A01, B11, acc[0][1]);
        acc[1][0] = mfma3216(A11, B10, acc[1][0]);
        acc[1][1] = mfma3216(A11, B11, acc[1][1]);
      }
      // ---- odd gg: h = 4p+2, 4p+3 ----
      {
        half8 B00 = *(const half8*)(Wp + (size_t)(sb + 2) * 2048 + woff0);
        half8 B01 = *(const half8*)(Wp + (size_t)(sb + 2) * 2048 + woff1);
        half8 B10 = *(const half8*)(Wp + (size_t)(sb + 3) * 2048 + woff0);
        half8 B11 = *(const half8*)(Wp + (size_t)(sb + 3) * 2048 + woff1);
        half8 A00 = P[0] * xq[4];  // rt0, h=4p+2
        half8 A10 = P[1] * xq[6];  // rt1, h=4p+2
        half8 A01 = P[0] * xq[5];  // rt0, h=4p+3
        half8 A11 = P[1] * xq[7];  // rt1, h=4p+3
        acc[0][0] = mfma3216(A00, B00, acc[0][0]);
        acc[0][1] = mfma3216(A00, B01, acc[0][1]);
        acc[1][0] = mfma3216(A10, B00, acc[1][0]);
        acc[1][1] = mfma3216(A10, B01, acc[1][1]);
        acc[0][0] = mfma3216(A01, B10, acc[0][0]);
        acc[0][1] = mfma3216(A01, B11, acc[0][1]);
        acc[1][0] = mfma3216(A11, B10, acc[1][0]);
        acc[1][1] = mfma3216(A11, B11, acc[1][1]);
      }
    }
    if (mc + 1 < MC) {
      const int mn = (mc + 1) * 16;
#pragma unroll
      for (int rt = 0; rt < 2; ++rt)
        P[rt] = L1 ? *(const half8*)&psrc[(rowb + rt * 32 + l31) * 40 + mn +
                                          hi * 8]
                   : *(const half8*)&psrc[pswz(rowb + rt * 32 + l31,
                                               mn + hi * 8)];
    }
  }
}

__global__ __launch_bounds__(256, 4) void cin_fused_kernel(
    const float* __restrict__ x0,    // [4096][32][32] fp32
    const half_t* __restrict__ Wp0,  // 64*2048 halfs
    const half_t* __restrict__ Wp1,  // 256*2048 halfs
    float* __restrict__ out) {       // [4096][256]
  // xQ[pair][p(8)][d(32)][ (hp&1)*4 + rtl*2 + (h&1) ]  (8 KB)
  __shared__ half_t xQ[2 * 8 * 32 * 8];
  // prevT: swizzled [4b*32d rows][128 m] (32 KB); aliased by xT (stride 40)
  __shared__ half_t prevT[4 * 32 * 128];
  half_t* xT = prevT;  // [bi*32+d][h], stride 40 halfs (4*32*40 = 5120 fits)

  const int tid = threadIdx.x;
  const int b0 = blockIdx.x * 4;

  // ---- stage x0 -> xQ and xT (4 b = 4096 floats = 1024 float4) ----
  const float4* x4 = (const float4*)(x0 + (size_t)b0 * 1024);
#pragma unroll
  for (int r = 0; r < 4; ++r) {
    int q = r * 256 + tid;
    float4 v = x4[q];
    int e4 = q * 4;
    int bi = e4 >> 10, h = (e4 >> 5) & 31, d0 = e4 & 31;
    half4v hv = {(half_t)v.x, (half_t)v.y, (half_t)v.z, (half_t)v.w};
    const int pair = bi >> 1, rtl = bi & 1;
    const int pp = h >> 2, hpar = (h >> 1) & 1, par = h & 1;
#pragma unroll
    for (int j = 0; j < 4; ++j) {
      xQ[pair * 2048 + pp * 256 + (d0 + j) * 8 + hpar * 4 + rtl * 2 + par] =
          hv[j];
      xT[(bi * 32 + d0 + j) * 40 + h] = hv[j];
    }
  }
  __syncthreads();

  const int lane = tid & 63;
  const int l31 = lane & 31;
  const int hi = lane >> 5;
  const int wave = tid >> 6;
  const int wr = wave >> 1;  // b-pair: b's wr*2, wr*2+1
  const int wc = wave & 1;   // col half: n in [wc*64, wc*64+64)

  const int woff0 = hi * 1024 + (wc * 64 + l31) * 8;       // ct=0 B offset
  const int woff1 = hi * 1024 + (wc * 64 + 32 + l31) * 8;  // ct=1 B offset
  const int rowb = wr * 64;                                // P row base
  const half_t* xQw = xQ + wr * 2048 + l31 * 8;

  f32x16 acc[2][2];
#pragma unroll
  for (int rt = 0; rt < 2; ++rt)
#pragma unroll
    for (int ct = 0; ct < 2; ++ct)
#pragma unroll
      for (int r = 0; r < 16; ++r) acc[rt][ct][r] = 0.f;

  // ================= layer 1 =================
  layer_loop<2, true>(Wp0, xT, xQw, woff0, woff1, rowb, l31, hi, acc);

  __syncthreads();  // all waves done reading xT before prevT overwrite

  // ---- epilogue 1: relu, cur1 -> prevT (swizzled), d-sum -> out[:, 0:128] ----
#pragma unroll
  for (int rt = 0; rt < 2; ++rt) {
#pragma unroll
    for (int ct = 0; ct < 2; ++ct) {
      float s = 0.f;
#pragma unroll
      for (int r = 0; r < 16; ++r) {
        float v = acc[rt][ct][r];
        v = v > 0.f ? v : 0.f;
        s += v;
        int d = (r & 3) + ((r >> 2) << 3) + hi * 4;  // C/D row map (32x32)
        prevT[pswz(rowb + rt * 32 + d, wc * 64 + ct * 32 + l31)] = (half_t)v;
        acc[rt][ct][r] = 0.f;
      }
      s += __shfl_down(s, 32);
      if (lane < 32)
        out[(size_t)(b0 + wr * 2 + rt) * 256 + wc * 64 + ct * 32 + lane] = s;
    }
  }
  __syncthreads();

  // ================= layer 2 =================
  layer_loop<8, false>(Wp1, prevT, xQw, woff0, woff1, rowb, l31, hi, acc);

  // ---- epilogue 2: relu, d-sum -> out[:, 128:256] ----
#pragma unroll
  for (int rt = 0; rt < 2; ++rt) {
#pragma unroll
    for (int ct = 0; ct < 2; ++ct) {
      float s = 0.f;
#pragma unroll
      for (int r = 0; r < 16; ++r) {
        float v = acc[rt][ct][r];
        s += v > 0.f ? v : 0.f;
      }
      s += __shfl_down(s, 32);
      if (lane < 32)
        out[(size_t)(b0 + wr * 2 + rt) * 256 + 128 + wc * 64 + ct * 32 +
            lane] = s;
    }
  }
}

extern "C" void kernel_launch(void* const* d_in, const int* in_sizes, int n_in,
                              void* d_out, int out_size, void* d_ws,
                              size_t ws_size, hipStream_t stream) {
  const float* x0 = (const float*)d_in[0];  // [4096,32,32]
  const float* w0 = (const float*)d_in[1];  // [1,1024,128]
  const float* w1 = (const float*)d_in[2];  // [1,4096,128]
  float* out = (float*)d_out;               // [4096,256]
  char* ws = (char*)d_ws;

  half_t* Wp0 = (half_t*)(ws);                  // 64*2048 f16 = 256 KB
  half_t* Wp1 = (half_t*)(ws + 64 * 2048 * 2);  // 256*2048 f16 = 1 MB

  hipLaunchKernelGGL(prep_w_kernel, dim3(320), dim3(256), 0, stream, w0, w1,
                     Wp0, Wp1);
  hipLaunchKernelGGL(cin_fused_kernel, dim3(1024), dim3(256), 0, stream, x0,
                     Wp0, Wp1, out);
}

// Round 7
// 204.063 us; speedup vs baseline: 1.1311x; 1.1311x over previous
//
#include <hip/hip_runtime.h>

// CIN (xDeepFM) fully-fused kernel for MI355X.
// B=4096, F=32, D=32; layer1: K1=1024 -> N=128; layer2: K2=4096 -> N=128.
// GEMM rows=(b,d); A generated in registers: A[(b,d)][h*M+m] = x0[b,h,d]*prev[b,m,d].
// mfma_f32_32x32x16_f16.
// History: R10 (pk_mul 4->2/MFMA) neutral; R11 setprio neutral; R13 pinned
// interleave REGRESSED; R14 (rt=2, 4 waves/SIMD, JIT B loads) REGRESSED
// (fused 137->172, MfmaUtil 47) despite 2x occupancy -- its per-CU B VMEM
// traffic doubled (~10.5 MB ~= entire MFMA pipe time at ~64 B/cyc) and
// prefetch went to 0. Conclusion: the binding residual is the B-operand
// VMEM path (request count + latency exposure), NOT A-gen VALU (tested
// free) and NOT intra-wave scheduling (3x null).
// R15 (resubmit -- R6 bench was an infra failure, no data): tile (rt,ct) =
// (8,1). loads/MFMA = 1/rt = 0.125 (HALF of R10), pk_mul/MFMA = 4/ct = 4
// (proven free). Wave owns all 8b x 32d rows and a 32-col slice. B ring =
// 4 half8 (16 VGPR), prefetched 4 s-steps (~2000 cyc) ahead. acc 128 AGPR
// + ~100 arch VGPR -> 2 waves/SIMD. Block = 8 b x 128 n (4 waves = col
// slices), LDS 80 KB, grid 512.

typedef _Float16 half_t;
typedef _Float16 half4v __attribute__((ext_vector_type(4)));
typedef _Float16 half8 __attribute__((ext_vector_type(8)));
typedef float f32x16 __attribute__((ext_vector_type(16)));

// ---- W pack (both filters, one launch): Wp[s][tg][n][8], k=h*M+mc*16+tg*8+j.
__global__ void prep_w_kernel(const float* __restrict__ W0,
                              const float* __restrict__ W1,
                              half_t* __restrict__ Wp0,
                              half_t* __restrict__ Wp1) {
  int gid = blockIdx.x * 256 + threadIdx.x;  // 320*256 threads
  int n = gid & 127;
  int tg = (gid >> 7) & 1;
  int s = gid >> 8;  // 0..319
  const float* W;
  half_t* Wp;
  int M, sl;
  if (s < 64) { W = W0; Wp = Wp0; M = 32; sl = s; }
  else        { W = W1; Wp = Wp1; M = 128; sl = s - 64; }
  int h = sl & 31, mc = sl >> 5;
  int kbase = h * M + mc * 16 + tg * 8;
  half8 v;
#pragma unroll
  for (int j = 0; j < 8; ++j) v[j] = (half_t)W[(size_t)(kbase + j) * 128 + n];
  *(half8*)(Wp + ((size_t)(sl * 2 + tg) * 128 + n) * 8) = v;
}

// swizzled prevT index: logical (row, m) -> halfs offset. 16B-chunk XOR spread.
__device__ __forceinline__ int pswz(int row, int m) {
  return row * 128 + (((m >> 3) ^ (row & 15)) << 3) + (m & 7);
}

__device__ __forceinline__ f32x16 mfma3216(half8 a, half8 b, f32x16 c) {
  return __builtin_amdgcn_mfma_f32_32x32x16_f16(a, b, c, 0, 0, 0);
}

// One CIN layer, (rt,ct)=(8,1). Per s-step: 8 A-frags (32 pk_mul), 8 MFMAs
// sharing ONE B frag, then refill that ring slot 4 s-steps ahead.
// P[8] = prev rows (bi=rt, d=l31), k-slice mc*16 + hi*8. xq via LDS:
// xQ[h][d][bi] -> one half8 gives x0[b=0..7, h, d=l31].
template <int MC, bool L1>
__device__ __forceinline__ void layer_loop(const half_t* __restrict__ Wp,
                                           const half_t* __restrict__ psrc,
                                           const half_t* __restrict__ xQb,
                                           int woff, int l31, int hi,
                                           f32x16 acc[8]) {
  half8 P[8];
#pragma unroll
  for (int rt = 0; rt < 8; ++rt)
    P[rt] = L1 ? *(const half8*)&psrc[(rt * 32 + l31) * 40 + hi * 8]
               : *(const half8*)&psrc[pswz(rt * 32 + l31, hi * 8)];

  // B ring, depth 4 (s-steps sb..sb+3), prefetch distance 4.
  half8 Br0 = *(const half8*)(Wp + (size_t)0 * 2048 + woff);
  half8 Br1 = *(const half8*)(Wp + (size_t)1 * 2048 + woff);
  half8 Br2 = *(const half8*)(Wp + (size_t)2 * 2048 + woff);
  half8 Br3 = *(const half8*)(Wp + (size_t)3 * 2048 + woff);

#pragma unroll 1
  for (int mc = 0; mc < MC; ++mc) {
#pragma unroll 1
    for (int p = 0; p < 8; ++p) {
      const int h0 = p * 4;
      const int sb = mc * 32 + h0;  // multiple of 4 -> ring slots align
      half8 xq0 = *(const half8*)(xQb + (h0 + 0) * 256);
      half8 xq1 = *(const half8*)(xQb + (h0 + 1) * 256);
      half8 xq2 = *(const half8*)(xQb + (h0 + 2) * 256);
      half8 xq3 = *(const half8*)(xQb + (h0 + 3) * 256);

#define SSTEP(XQ, BR, OFFJ)                                               \
  {                                                                       \
    half8 A0 = P[0] * XQ[0], A1 = P[1] * XQ[1], A2 = P[2] * XQ[2],        \
          A3 = P[3] * XQ[3];                                              \
    acc[0] = mfma3216(A0, BR, acc[0]);                                    \
    acc[1] = mfma3216(A1, BR, acc[1]);                                    \
    acc[2] = mfma3216(A2, BR, acc[2]);                                    \
    acc[3] = mfma3216(A3, BR, acc[3]);                                    \
    half8 A4 = P[4] * XQ[4], A5 = P[5] * XQ[5], A6 = P[6] * XQ[6],        \
          A7 = P[7] * XQ[7];                                              \
    acc[4] = mfma3216(A4, BR, acc[4]);                                    \
    acc[5] = mfma3216(A5, BR, acc[5]);                                    \
    acc[6] = mfma3216(A6, BR, acc[6]);                                    \
    acc[7] = mfma3216(A7, BR, acc[7]);                                    \
    BR = *(const half8*)(Wp +                                             \
                         (size_t)((sb + 4 + OFFJ) & (MC * 32 - 1)) * 2048 \
                         + woff);                                         \
  }
      SSTEP(xq0, Br0, 0)
      SSTEP(xq1, Br1, 1)
      SSTEP(xq2, Br2, 2)
      SSTEP(xq3, Br3, 3)
#undef SSTEP
    }
    if (mc + 1 < MC) {
      const int mn = (mc + 1) * 16;
#pragma unroll
      for (int rt = 0; rt < 8; ++rt)
        P[rt] = L1 ? *(const half8*)&psrc[(rt * 32 + l31) * 40 + mn + hi * 8]
                   : *(const half8*)&psrc[pswz(rt * 32 + l31, mn + hi * 8)];
    }
  }
}

__global__ __launch_bounds__(256, 2) void cin_fused_kernel(
    const float* __restrict__ x0,    // [4096][32][32] fp32
    const half_t* __restrict__ Wp0,  // 64*2048 halfs
    const half_t* __restrict__ Wp1,  // 256*2048 halfs
    float* __restrict__ out) {       // [4096][256]
  __shared__ half_t xQ[32 * 32 * 8];      // [h][d][bi] (16 KB)
  __shared__ half_t prevT[8 * 32 * 128];  // swizzled [bi][d][m] (64 KB); alias xT
  half_t* xT = prevT;                     // [bi*32+d][h], stride 40 halfs

  const int tid = threadIdx.x;
  const int b0 = blockIdx.x * 8;

  // ---- stage x0 -> xQ and xT (8 b = 8192 floats = 2048 float4) ----
  const float4* x4 = (const float4*)(x0 + (size_t)b0 * 1024);
#pragma unroll
  for (int r = 0; r < 8; ++r) {
    int q = r * 256 + tid;
    float4 v = x4[q];
    int e4 = q * 4;
    int bi = e4 >> 10, h = (e4 >> 5) & 31, d0 = e4 & 31;
    half4v hv = {(half_t)v.x, (half_t)v.y, (half_t)v.z, (half_t)v.w};
#pragma unroll
    for (int j = 0; j < 4; ++j) {
      xQ[(h * 32 + d0 + j) * 8 + bi] = hv[j];
      xT[(bi * 32 + d0 + j) * 40 + h] = hv[j];
    }
  }
  __syncthreads();

  const int lane = tid & 63;
  const int l31 = lane & 31;
  const int hi = lane >> 5;
  const int wave = tid >> 6;  // col slice: n in [wave*32, wave*32+32)

  const int woff = hi * 1024 + (wave * 32 + l31) * 8;  // B frag offset
  const half_t* xQb = xQ + l31 * 8;                    // + h*256 per h

  f32x16 acc[8];
#pragma unroll
  for (int rt = 0; rt < 8; ++rt)
#pragma unroll
    for (int r = 0; r < 16; ++r) acc[rt][r] = 0.f;

  // ================= layer 1 =================
  layer_loop<2, true>(Wp0, xT, xQb, woff, l31, hi, acc);

  __syncthreads();  // all waves done reading xT before prevT overwrite

  // ---- epilogue 1: relu, cur1 -> prevT (swizzled), d-sum -> out[:, 0:128] ----
#pragma unroll
  for (int rt = 0; rt < 8; ++rt) {
    float s = 0.f;
#pragma unroll
    for (int r = 0; r < 16; ++r) {
      float v = acc[rt][r];
      v = v > 0.f ? v : 0.f;
      s += v;
      int d = (r & 3) + ((r >> 2) << 3) + hi * 4;  // C/D row map (32x32)
      prevT[pswz(rt * 32 + d, wave * 32 + l31)] = (half_t)v;
      acc[rt][r] = 0.f;
    }
    s += __shfl_down(s, 32);
    if (lane < 32)
      out[(size_t)(b0 + rt) * 256 + wave * 32 + lane] = s;
  }
  __syncthreads();

  // ================= layer 2 =================
  layer_loop<8, false>(Wp1, prevT, xQb, woff, l31, hi, acc);

  // ---- epilogue 2: relu, d-sum -> out[:, 128:256] ----
#pragma unroll
  for (int rt = 0; rt < 8; ++rt) {
    float s = 0.f;
#pragma unroll
    for (int r = 0; r < 16; ++r) {
      float v = acc[rt][r];
      s += v > 0.f ? v : 0.f;
    }
    s += __shfl_down(s, 32);
    if (lane < 32)
      out[(size_t)(b0 + rt) * 256 + 128 + wave * 32 + lane] = s;
  }
}

extern "C" void kernel_launch(void* const* d_in, const int* in_sizes, int n_in,
                              void* d_out, int out_size, void* d_ws,
                              size_t ws_size, hipStream_t stream) {
  const float* x0 = (const float*)d_in[0];  // [4096,32,32]
  const float* w0 = (const float*)d_in[1];  // [1,1024,128]
  const float* w1 = (const float*)d_in[2];  // [1,4096,128]
  float* out = (float*)d_out;               // [4096,256]
  char* ws = (char*)d_ws;

  half_t* Wp0 = (half_t*)(ws);                  // 64*2048 f16 = 256 KB
  half_t* Wp1 = (half_t*)(ws + 64 * 2048 * 2);  // 256*2048 f16 = 1 MB

  hipLaunchKernelGGL(prep_w_kernel, dim3(320), dim3(256), 0, stream, w0, w1,
                     Wp0, Wp1);
  hipLaunchKernelGGL(cin_fused_kernel, dim3(512), dim3(256), 0, stream, x0,
                     Wp0, Wp1, out);
}